// Round 3
// baseline (823.278 us; speedup 1.0000x reference)
//
#include <hip/hip_runtime.h>
#include <math.h>

#define RDIM 192
#define FDIM 28
#define PTS_PER_BLOCK 32   // gather kernel: 256 threads, 8 lanes per point

#define BSHIFT 3                         // 8-cell buckets
#define BDIM   (RDIM >> BSHIFT)          // 24
#define NBUCKET (BDIM * BDIM * BDIM)     // 13824

// SH constants (match reference)
#define SH_C0  0.28209479177387814f
#define SH_C1  0.4886025119029199f
#define SH_C2  0.5462742152960396f
#define SH_C20 0.15769578262626154f
#define SH_C22 0.2731371076480198f

__device__ __forceinline__ void cell_of(float px, float py, float pz,
                                        int& x0, int& y0, int& z0) {
    const float A = (RDIM - 1) / 8.0f;   // 23.875
    const float B = (RDIM - 1) * 0.5f;   // 95.5
    const float RM1 = (float)(RDIM - 1);
    float cx = fminf(fmaxf(px * A + B, 0.0f), RM1);
    float cy = fminf(fmaxf(py * A + B, 0.0f), RM1);
    float cz = fminf(fmaxf(pz * A + B, 0.0f), RM1);
    x0 = (int)floorf(cx);
    y0 = (int)floorf(cy);
    z0 = (int)floorf(cz);
}

__device__ __forceinline__ int bucket_of(int x0, int y0, int z0) {
    return ((z0 >> BSHIFT) * BDIM + (y0 >> BSHIFT)) * BDIM + (x0 >> BSHIFT);
}

// ---------------------------------------------------------------- zero hist
__global__ __launch_bounds__(256)
void zero_hist(int* __restrict__ hist) {
    int i = blockIdx.x * 256 + threadIdx.x;
    if (i < NBUCKET) hist[i] = 0;
}

// ---------------------------------------------------------------- histogram
__global__ __launch_bounds__(256)
void hist_kernel(const float* __restrict__ points, int* __restrict__ hist, int N) {
    int i = blockIdx.x * 256 + threadIdx.x;
    if (i >= N) return;
    float px = points[3 * i + 0];
    float py = points[3 * i + 1];
    float pz = points[3 * i + 2];
    int x0, y0, z0;
    cell_of(px, py, pz, x0, y0, z0);
    atomicAdd(&hist[bucket_of(x0, y0, z0)], 1);
}

// ---------------------------------------------------------------- scan (1 block)
#define SCAN_T 1024
#define SCAN_V 14   // 1024*14 = 14336 >= 13824
__global__ __launch_bounds__(SCAN_T)
void scan_kernel(const int* __restrict__ hist, int* __restrict__ offs) {
    __shared__ int lds[SCAN_T];
    int t = threadIdx.x;
    int base = t * SCAN_V;
    int v[SCAN_V];
    int s = 0;
#pragma unroll
    for (int k = 0; k < SCAN_V; ++k) {
        int idx = base + k;
        v[k] = (idx < NBUCKET) ? hist[idx] : 0;
        s += v[k];
    }
    lds[t] = s;
    __syncthreads();
    // Hillis-Steele inclusive scan over 1024 thread-sums
    for (int off = 1; off < SCAN_T; off <<= 1) {
        int add = (t >= off) ? lds[t - off] : 0;
        __syncthreads();
        lds[t] += add;
        __syncthreads();
    }
    int excl = (t == 0) ? 0 : lds[t - 1];
#pragma unroll
    for (int k = 0; k < SCAN_V; ++k) {
        int idx = base + k;
        if (idx < NBUCKET) offs[idx] = excl;
        excl += v[k];
    }
}

// ---------------------------------------------------------------- scatter
__global__ __launch_bounds__(256)
void scatter_kernel(const float* __restrict__ points, int* __restrict__ offs,
                    float4* __restrict__ sorted, int N) {
    int i = blockIdx.x * 256 + threadIdx.x;
    if (i >= N) return;
    float px = points[3 * i + 0];
    float py = points[3 * i + 1];
    float pz = points[3 * i + 2];
    int x0, y0, z0;
    cell_of(px, py, pz, x0, y0, z0);
    int pos = atomicAdd(&offs[bucket_of(x0, y0, z0)], 1);
    sorted[pos] = make_float4(px, py, pz, __int_as_float(i));
}

// ---------------------------------------------------------------- gather + shade
__global__ __launch_bounds__(256)
void plenoxel_fwd(const float4* __restrict__ sorted,
                  const float* __restrict__ voxels,
                  float* __restrict__ out_rgb,    // N*3
                  float* __restrict__ out_sigma,  // N
                  int N)
{
    __shared__ float feats[PTS_PER_BLOCK][FDIM];  // 3.5 KB

    const int tid   = threadIdx.x;
    const int group = tid >> 3;   // 0..31 : point within block
    const int f     = tid & 7;    // 0..7  : feature-quad (7 idle for loads)
    const int p     = blockIdx.x * PTS_PER_BLOCK + group;

    if (p < N && f < 7) {
        float4 pt = sorted[p];
        float px = pt.x, py = pt.y, pz = pt.z;

        int x0, y0, z0;
        cell_of(px, py, pz, x0, y0, z0);
        const float A = (RDIM - 1) / 8.0f;
        const float B = (RDIM - 1) * 0.5f;
        const float RM1 = (float)(RDIM - 1);
        float cx = fminf(fmaxf(px * A + B, 0.0f), RM1);
        float cy = fminf(fmaxf(py * A + B, 0.0f), RM1);
        float cz = fminf(fmaxf(pz * A + B, 0.0f), RM1);
        float fx = cx - (float)x0, fy = cy - (float)y0, fz = cz - (float)z0;
        int x1 = min(x0 + 1, RDIM - 1);
        int y1 = min(y0 + 1, RDIM - 1);
        int z1 = min(z0 + 1, RDIM - 1);

        float gx = 1.0f - fx, gy = 1.0f - fy, gz = 1.0f - fz;

        float w000 = gz * gy * gx;
        float w001 = gz * gy * fx;
        float w010 = gz * fy * gx;
        float w011 = gz * fy * fx;
        float w100 = fz * gy * gx;
        float w101 = fz * gy * fx;
        float w110 = fz * fy * gx;
        float w111 = fz * fy * fx;

        int b000 = ((z0 * RDIM + y0) * RDIM + x0) * FDIM;
        int b001 = ((z0 * RDIM + y0) * RDIM + x1) * FDIM;
        int b010 = ((z0 * RDIM + y1) * RDIM + x0) * FDIM;
        int b011 = ((z0 * RDIM + y1) * RDIM + x1) * FDIM;
        int b100 = ((z1 * RDIM + y0) * RDIM + x0) * FDIM;
        int b101 = ((z1 * RDIM + y0) * RDIM + x1) * FDIM;
        int b110 = ((z1 * RDIM + y1) * RDIM + x0) * FDIM;
        int b111 = ((z1 * RDIM + y1) * RDIM + x1) * FDIM;

        const float4* __restrict__ src = (const float4*)voxels;

        float4 v0 = src[(b000 >> 2) + f];
        float4 v1 = src[(b001 >> 2) + f];
        float4 v2 = src[(b010 >> 2) + f];
        float4 v3 = src[(b011 >> 2) + f];
        float4 v4 = src[(b100 >> 2) + f];
        float4 v5 = src[(b101 >> 2) + f];
        float4 v6 = src[(b110 >> 2) + f];
        float4 v7 = src[(b111 >> 2) + f];

        float4 acc;
        acc.x = w000 * v0.x + w001 * v1.x + w010 * v2.x + w011 * v3.x
              + w100 * v4.x + w101 * v5.x + w110 * v6.x + w111 * v7.x;
        acc.y = w000 * v0.y + w001 * v1.y + w010 * v2.y + w011 * v3.y
              + w100 * v4.y + w101 * v5.y + w110 * v6.y + w111 * v7.y;
        acc.z = w000 * v0.z + w001 * v1.z + w010 * v2.z + w011 * v3.z
              + w100 * v4.z + w101 * v5.z + w110 * v6.z + w111 * v7.z;
        acc.w = w000 * v0.w + w001 * v1.w + w010 * v2.w + w011 * v3.w
              + w100 * v4.w + w101 * v5.w + w110 * v6.w + w111 * v7.w;

        *(float4*)&feats[group][4 * f] = acc;
    }

    __syncthreads();

    if (tid < PTS_PER_BLOCK) {
        int p2 = blockIdx.x * PTS_PER_BLOCK + tid;
        if (p2 < N) {
            float4 pt = sorted[p2];
            float px = pt.x, py = pt.y, pz = pt.z;
            int oi = __float_as_int(pt.w);

            float inv = rsqrtf(px * px + py * py + pz * pz);
            float dx = px * inv, dy = py * inv, dz = pz * inv;

            float basis[9];
            basis[0] = SH_C0;
            basis[1] = SH_C1 * dy;
            basis[2] = SH_C1 * dz;
            basis[3] = SH_C1 * dx;
            basis[4] = SH_C2 * dx * dy;
            basis[5] = SH_C2 * dy * dz;
            basis[6] = SH_C20 * (3.0f * dz * dz - 1.0f);
            basis[7] = SH_C2 * dx * dz;
            basis[8] = SH_C22 * (dx * dx - dy * dy);

#pragma unroll
            for (int c = 0; c < 3; ++c) {
                float s = 0.0f;
#pragma unroll
                for (int j = 0; j < 9; ++j) {
                    s += feats[tid][1 + 9 * c + j] * basis[j];
                }
                out_rgb[3 * oi + c] = 1.0f / (1.0f + expf(-s));
            }

            float x = feats[tid][0];
            out_sigma[oi] = fmaxf(x, 0.0f) + log1pf(expf(-fabsf(x)));
        }
    }
}

extern "C" void kernel_launch(void* const* d_in, const int* in_sizes, int n_in,
                              void* d_out, int out_size, void* d_ws, size_t ws_size,
                              hipStream_t stream) {
    const float* points = (const float*)d_in[0];
    const float* voxels = (const float*)d_in[1];
    int N = in_sizes[0] / 3;

    float* out_rgb = (float*)d_out;              // N*3
    float* out_sigma = out_rgb + (size_t)3 * N;  // N

    // workspace layout (ws is ~3 GB, we need ~32 MB)
    char* ws = (char*)d_ws;
    float4* sorted = (float4*)ws;                        // N * 16B
    int* hist = (int*)(ws + (size_t)N * 16);             // NBUCKET * 4B
    int* offs = hist + NBUCKET;                          // NBUCKET * 4B

    int pblocks = (N + 255) / 256;

    zero_hist<<<(NBUCKET + 255) / 256, 256, 0, stream>>>(hist);
    hist_kernel<<<pblocks, 256, 0, stream>>>(points, hist, N);
    scan_kernel<<<1, SCAN_T, 0, stream>>>(hist, offs);
    scatter_kernel<<<pblocks, 256, 0, stream>>>(points, offs, sorted, N);

    int gblocks = (N + PTS_PER_BLOCK - 1) / PTS_PER_BLOCK;
    plenoxel_fwd<<<gblocks, 256, 0, stream>>>(sorted, voxels, out_rgb, out_sigma, N);
}

// Round 4
// 775.376 us; speedup vs baseline: 1.0618x; 1.0618x over previous
//
#include <hip/hip_runtime.h>
#include <math.h>

#define RDIM 192
#define FDIM 28
#define PTS_PER_BLOCK 32   // gather kernel: 256 threads, 8 lanes per point

#define BSHIFT 3                         // 8-cell buckets
#define BDIM   (RDIM >> BSHIFT)          // 24
#define NBUCKET (BDIM * BDIM * BDIM)     // 13824

// SH constants (match reference)
#define SH_C0  0.28209479177387814f
#define SH_C1  0.4886025119029199f
#define SH_C2  0.5462742152960396f
#define SH_C20 0.15769578262626154f
#define SH_C22 0.2731371076480198f

__device__ __forceinline__ void cell_of(float px, float py, float pz,
                                        int& x0, int& y0, int& z0) {
    const float A = (RDIM - 1) / 8.0f;   // 23.875
    const float B = (RDIM - 1) * 0.5f;   // 95.5
    const float RM1 = (float)(RDIM - 1);
    float cx = fminf(fmaxf(px * A + B, 0.0f), RM1);
    float cy = fminf(fmaxf(py * A + B, 0.0f), RM1);
    float cz = fminf(fmaxf(pz * A + B, 0.0f), RM1);
    x0 = (int)floorf(cx);
    y0 = (int)floorf(cy);
    z0 = (int)floorf(cz);
}

__device__ __forceinline__ int bucket_of(int x0, int y0, int z0) {
    return ((z0 >> BSHIFT) * BDIM + (y0 >> BSHIFT)) * BDIM + (x0 >> BSHIFT);
}

// ---------------------------------------------------------------- zero hist
__global__ __launch_bounds__(256)
void zero_hist(int* __restrict__ hist) {
    int i = blockIdx.x * 256 + threadIdx.x;
    if (i < NBUCKET) hist[i] = 0;
}

// ---------------------------------------------------------------- histogram
__global__ __launch_bounds__(256)
void hist_kernel(const float* __restrict__ points, int* __restrict__ hist, int N) {
    int i = blockIdx.x * 256 + threadIdx.x;
    if (i >= N) return;
    float px = points[3 * i + 0];
    float py = points[3 * i + 1];
    float pz = points[3 * i + 2];
    int x0, y0, z0;
    cell_of(px, py, pz, x0, y0, z0);
    atomicAdd(&hist[bucket_of(x0, y0, z0)], 1);
}

// ---------------------------------------------------------------- scan (1 block)
#define SCAN_T 1024
#define SCAN_V 14   // 1024*14 = 14336 >= 13824
__global__ __launch_bounds__(SCAN_T)
void scan_kernel(const int* __restrict__ hist, int* __restrict__ offs) {
    __shared__ int lds[SCAN_T];
    int t = threadIdx.x;
    int base = t * SCAN_V;
    int v[SCAN_V];
    int s = 0;
#pragma unroll
    for (int k = 0; k < SCAN_V; ++k) {
        int idx = base + k;
        v[k] = (idx < NBUCKET) ? hist[idx] : 0;
        s += v[k];
    }
    lds[t] = s;
    __syncthreads();
    for (int off = 1; off < SCAN_T; off <<= 1) {
        int add = (t >= off) ? lds[t - off] : 0;
        __syncthreads();
        lds[t] += add;
        __syncthreads();
    }
    int excl = (t == 0) ? 0 : lds[t - 1];
#pragma unroll
    for (int k = 0; k < SCAN_V; ++k) {
        int idx = base + k;
        if (idx < NBUCKET) offs[idx] = excl;
        excl += v[k];
    }
}

// ---------------------------------------------------------------- scatter
__global__ __launch_bounds__(256)
void scatter_kernel(const float* __restrict__ points, int* __restrict__ offs,
                    float4* __restrict__ sorted, int* __restrict__ rank, int N) {
    int i = blockIdx.x * 256 + threadIdx.x;
    if (i >= N) return;
    float px = points[3 * i + 0];
    float py = points[3 * i + 1];
    float pz = points[3 * i + 2];
    int x0, y0, z0;
    cell_of(px, py, pz, x0, y0, z0);
    int pos = atomicAdd(&offs[bucket_of(x0, y0, z0)], 1);
    sorted[pos] = make_float4(px, py, pz, 0.0f);
    rank[i] = pos;            // coalesced by i
}

// ---------------------------------------------------------------- gather + shade (coalesced tmp out)
__global__ __launch_bounds__(256)
void plenoxel_fwd(const float4* __restrict__ sorted,
                  const float* __restrict__ voxels,
                  float4* __restrict__ tmp,      // N x (r,g,b,sigma), sorted order
                  int N)
{
    __shared__ float feats[PTS_PER_BLOCK][FDIM];  // 3.5 KB

    const int tid   = threadIdx.x;
    const int group = tid >> 3;   // 0..31 : point within block
    const int f     = tid & 7;    // 0..7  : feature-quad (7 idle for loads)
    const int p     = blockIdx.x * PTS_PER_BLOCK + group;

    if (p < N && f < 7) {
        float4 pt = sorted[p];
        float px = pt.x, py = pt.y, pz = pt.z;

        int x0, y0, z0;
        cell_of(px, py, pz, x0, y0, z0);
        const float A = (RDIM - 1) / 8.0f;
        const float B = (RDIM - 1) * 0.5f;
        const float RM1 = (float)(RDIM - 1);
        float cx = fminf(fmaxf(px * A + B, 0.0f), RM1);
        float cy = fminf(fmaxf(py * A + B, 0.0f), RM1);
        float cz = fminf(fmaxf(pz * A + B, 0.0f), RM1);
        float fx = cx - (float)x0, fy = cy - (float)y0, fz = cz - (float)z0;
        int x1 = min(x0 + 1, RDIM - 1);
        int y1 = min(y0 + 1, RDIM - 1);
        int z1 = min(z0 + 1, RDIM - 1);

        float gx = 1.0f - fx, gy = 1.0f - fy, gz = 1.0f - fz;

        float w000 = gz * gy * gx;
        float w001 = gz * gy * fx;
        float w010 = gz * fy * gx;
        float w011 = gz * fy * fx;
        float w100 = fz * gy * gx;
        float w101 = fz * gy * fx;
        float w110 = fz * fy * gx;
        float w111 = fz * fy * fx;

        int b000 = ((z0 * RDIM + y0) * RDIM + x0) * FDIM;
        int b001 = ((z0 * RDIM + y0) * RDIM + x1) * FDIM;
        int b010 = ((z0 * RDIM + y1) * RDIM + x0) * FDIM;
        int b011 = ((z0 * RDIM + y1) * RDIM + x1) * FDIM;
        int b100 = ((z1 * RDIM + y0) * RDIM + x0) * FDIM;
        int b101 = ((z1 * RDIM + y0) * RDIM + x1) * FDIM;
        int b110 = ((z1 * RDIM + y1) * RDIM + x0) * FDIM;
        int b111 = ((z1 * RDIM + y1) * RDIM + x1) * FDIM;

        const float4* __restrict__ src = (const float4*)voxels;

        float4 v0 = src[(b000 >> 2) + f];
        float4 v1 = src[(b001 >> 2) + f];
        float4 v2 = src[(b010 >> 2) + f];
        float4 v3 = src[(b011 >> 2) + f];
        float4 v4 = src[(b100 >> 2) + f];
        float4 v5 = src[(b101 >> 2) + f];
        float4 v6 = src[(b110 >> 2) + f];
        float4 v7 = src[(b111 >> 2) + f];

        float4 acc;
        acc.x = w000 * v0.x + w001 * v1.x + w010 * v2.x + w011 * v3.x
              + w100 * v4.x + w101 * v5.x + w110 * v6.x + w111 * v7.x;
        acc.y = w000 * v0.y + w001 * v1.y + w010 * v2.y + w011 * v3.y
              + w100 * v4.y + w101 * v5.y + w110 * v6.y + w111 * v7.y;
        acc.z = w000 * v0.z + w001 * v1.z + w010 * v2.z + w011 * v3.z
              + w100 * v4.z + w101 * v5.z + w110 * v6.z + w111 * v7.z;
        acc.w = w000 * v0.w + w001 * v1.w + w010 * v2.w + w011 * v3.w
              + w100 * v4.w + w101 * v5.w + w110 * v6.w + w111 * v7.w;

        *(float4*)&feats[group][4 * f] = acc;
    }

    __syncthreads();

    if (tid < PTS_PER_BLOCK) {
        int p2 = blockIdx.x * PTS_PER_BLOCK + tid;
        if (p2 < N) {
            float4 pt = sorted[p2];
            float px = pt.x, py = pt.y, pz = pt.z;

            float inv = rsqrtf(px * px + py * py + pz * pz);
            float dx = px * inv, dy = py * inv, dz = pz * inv;

            float basis[9];
            basis[0] = SH_C0;
            basis[1] = SH_C1 * dy;
            basis[2] = SH_C1 * dz;
            basis[3] = SH_C1 * dx;
            basis[4] = SH_C2 * dx * dy;
            basis[5] = SH_C2 * dy * dz;
            basis[6] = SH_C20 * (3.0f * dz * dz - 1.0f);
            basis[7] = SH_C2 * dx * dz;
            basis[8] = SH_C22 * (dx * dx - dy * dy);

            float rgb[3];
#pragma unroll
            for (int c = 0; c < 3; ++c) {
                float s = 0.0f;
#pragma unroll
                for (int j = 0; j < 9; ++j) {
                    s += feats[tid][1 + 9 * c + j] * basis[j];
                }
                rgb[c] = 1.0f / (1.0f + expf(-s));
            }

            float x = feats[tid][0];
            float sig = fmaxf(x, 0.0f) + log1pf(expf(-fabsf(x)));

            tmp[p2] = make_float4(rgb[0], rgb[1], rgb[2], sig);  // coalesced
        }
    }
}

// ---------------------------------------------------------------- permute back
__global__ __launch_bounds__(256)
void permute_kernel(const float4* __restrict__ tmp, const int* __restrict__ rank,
                    float* __restrict__ out_rgb, float* __restrict__ out_sigma, int N) {
    int i = blockIdx.x * 256 + threadIdx.x;
    if (i >= N) return;
    float4 v = tmp[rank[i]];   // scattered 16B read, tmp (32MB) is L3-resident
    out_rgb[3 * i + 0] = v.x;  // coalesced writes
    out_rgb[3 * i + 1] = v.y;
    out_rgb[3 * i + 2] = v.z;
    out_sigma[i] = v.w;
}

extern "C" void kernel_launch(void* const* d_in, const int* in_sizes, int n_in,
                              void* d_out, int out_size, void* d_ws, size_t ws_size,
                              hipStream_t stream) {
    const float* points = (const float*)d_in[0];
    const float* voxels = (const float*)d_in[1];
    int N = in_sizes[0] / 3;

    float* out_rgb = (float*)d_out;              // N*3
    float* out_sigma = out_rgb + (size_t)3 * N;  // N

    // workspace layout (~72 MB of the ~3 GB ws)
    char* ws = (char*)d_ws;
    float4* sorted = (float4*)ws;                          // N*16B
    float4* tmp    = (float4*)(ws + (size_t)N * 16);       // N*16B
    int*    rank   = (int*)(ws + (size_t)N * 32);          // N*4B
    int*    hist   = (int*)(ws + (size_t)N * 36);          // NBUCKET*4B
    int*    offs   = hist + NBUCKET;                       // NBUCKET*4B

    int pblocks = (N + 255) / 256;

    zero_hist<<<(NBUCKET + 255) / 256, 256, 0, stream>>>(hist);
    hist_kernel<<<pblocks, 256, 0, stream>>>(points, hist, N);
    scan_kernel<<<1, SCAN_T, 0, stream>>>(hist, offs);
    scatter_kernel<<<pblocks, 256, 0, stream>>>(points, offs, sorted, rank, N);

    int gblocks = (N + PTS_PER_BLOCK - 1) / PTS_PER_BLOCK;
    plenoxel_fwd<<<gblocks, 256, 0, stream>>>(sorted, voxels, tmp, N);

    permute_kernel<<<pblocks, 256, 0, stream>>>(tmp, rank, out_rgb, out_sigma, N);
}

// Round 5
// 615.382 us; speedup vs baseline: 1.3378x; 1.2600x over previous
//
#include <hip/hip_runtime.h>
#include <math.h>

#define RDIM 192
#define FDIM 28
#define PTS_PER_BLOCK 32   // gather kernel: 256 threads, 8 lanes per point

#define BSHIFT 3                         // 8-cell buckets
#define BDIM   (RDIM >> BSHIFT)          // 24
#define NBUCKET (BDIM * BDIM * BDIM)     // 13824
#define NSHARD  16                       // counter shards (anti-contention)
#define HTOT    (NBUCKET * NSHARD)       // 221184

// SH constants (match reference)
#define SH_C0  0.28209479177387814f
#define SH_C1  0.4886025119029199f
#define SH_C2  0.5462742152960396f
#define SH_C20 0.15769578262626154f
#define SH_C22 0.2731371076480198f

__device__ __forceinline__ void cell_of(float px, float py, float pz,
                                        int& x0, int& y0, int& z0) {
    const float A = (RDIM - 1) / 8.0f;   // 23.875
    const float B = (RDIM - 1) * 0.5f;   // 95.5
    const float RM1 = (float)(RDIM - 1);
    float cx = fminf(fmaxf(px * A + B, 0.0f), RM1);
    float cy = fminf(fmaxf(py * A + B, 0.0f), RM1);
    float cz = fminf(fmaxf(pz * A + B, 0.0f), RM1);
    x0 = (int)floorf(cx);
    y0 = (int)floorf(cy);
    z0 = (int)floorf(cz);
}

__device__ __forceinline__ int bucket_of(int x0, int y0, int z0) {
    return ((z0 >> BSHIFT) * BDIM + (y0 >> BSHIFT)) * BDIM + (x0 >> BSHIFT);
}

// counter slot for point i in bucket b: shard by point-index high bits
__device__ __forceinline__ int slot_of(int b, int i) {
    return b * NSHARD + ((i >> 17) & (NSHARD - 1));
}

// ---------------------------------------------------------------- zero hist
__global__ __launch_bounds__(256)
void zero_hist(int* __restrict__ hist) {
    int i = blockIdx.x * 256 + threadIdx.x;
    if (i < HTOT) hist[i] = 0;
}

// ---------------------------------------------------------------- histogram
__global__ __launch_bounds__(256)
void hist_kernel(const float* __restrict__ points, int* __restrict__ hist, int N) {
    int i = blockIdx.x * 256 + threadIdx.x;
    if (i >= N) return;
    float px = points[3 * i + 0];
    float py = points[3 * i + 1];
    float pz = points[3 * i + 2];
    int x0, y0, z0;
    cell_of(px, py, pz, x0, y0, z0);
    atomicAdd(&hist[slot_of(bucket_of(x0, y0, z0), i)], 1);
}

// ---------------------------------------------------------------- scan (1 block, 221184 entries)
#define SCAN_T 1024
#define SCAN_V (HTOT / SCAN_T)   // 216
__global__ __launch_bounds__(SCAN_T)
void scan_kernel(const int* __restrict__ hist, int* __restrict__ offs) {
    __shared__ int lds[SCAN_T];
    int t = threadIdx.x;
    int base = t * SCAN_V;
    int s = 0;
    for (int k = 0; k < SCAN_V; ++k) s += hist[base + k];
    lds[t] = s;
    __syncthreads();
    for (int off = 1; off < SCAN_T; off <<= 1) {
        int add = (t >= off) ? lds[t - off] : 0;
        __syncthreads();
        lds[t] += add;
        __syncthreads();
    }
    int excl = (t == 0) ? 0 : lds[t - 1];
    for (int k = 0; k < SCAN_V; ++k) {
        int h = hist[base + k];
        offs[base + k] = excl;
        excl += h;
    }
}

// ---------------------------------------------------------------- scatter
__global__ __launch_bounds__(256)
void scatter_kernel(const float* __restrict__ points, int* __restrict__ offs,
                    float4* __restrict__ sorted, int* __restrict__ rank, int N) {
    int i = blockIdx.x * 256 + threadIdx.x;
    if (i >= N) return;
    float px = points[3 * i + 0];
    float py = points[3 * i + 1];
    float pz = points[3 * i + 2];
    int x0, y0, z0;
    cell_of(px, py, pz, x0, y0, z0);
    int pos = atomicAdd(&offs[slot_of(bucket_of(x0, y0, z0), i)], 1);
    sorted[pos] = make_float4(px, py, pz, 0.0f);
    rank[i] = pos;            // coalesced by i
}

// ---------------------------------------------------------------- gather + shade (coalesced tmp out)
__global__ __launch_bounds__(256)
void plenoxel_fwd(const float4* __restrict__ sorted,
                  const float* __restrict__ voxels,
                  float4* __restrict__ tmp,      // N x (r,g,b,sigma), sorted order
                  int N)
{
    __shared__ float feats[PTS_PER_BLOCK][FDIM];  // 3.5 KB

    const int tid   = threadIdx.x;
    const int group = tid >> 3;   // 0..31 : point within block
    const int f     = tid & 7;    // 0..7  : feature-quad (7 idle for loads)
    const int p     = blockIdx.x * PTS_PER_BLOCK + group;

    if (p < N && f < 7) {
        float4 pt = sorted[p];
        float px = pt.x, py = pt.y, pz = pt.z;

        int x0, y0, z0;
        cell_of(px, py, pz, x0, y0, z0);
        const float A = (RDIM - 1) / 8.0f;
        const float B = (RDIM - 1) * 0.5f;
        const float RM1 = (float)(RDIM - 1);
        float cx = fminf(fmaxf(px * A + B, 0.0f), RM1);
        float cy = fminf(fmaxf(py * A + B, 0.0f), RM1);
        float cz = fminf(fmaxf(pz * A + B, 0.0f), RM1);
        float fx = cx - (float)x0, fy = cy - (float)y0, fz = cz - (float)z0;
        int x1 = min(x0 + 1, RDIM - 1);
        int y1 = min(y0 + 1, RDIM - 1);
        int z1 = min(z0 + 1, RDIM - 1);

        float gx = 1.0f - fx, gy = 1.0f - fy, gz = 1.0f - fz;

        float w000 = gz * gy * gx;
        float w001 = gz * gy * fx;
        float w010 = gz * fy * gx;
        float w011 = gz * fy * fx;
        float w100 = fz * gy * gx;
        float w101 = fz * gy * fx;
        float w110 = fz * fy * gx;
        float w111 = fz * fy * fx;

        int b000 = ((z0 * RDIM + y0) * RDIM + x0) * FDIM;
        int b001 = ((z0 * RDIM + y0) * RDIM + x1) * FDIM;
        int b010 = ((z0 * RDIM + y1) * RDIM + x0) * FDIM;
        int b011 = ((z0 * RDIM + y1) * RDIM + x1) * FDIM;
        int b100 = ((z1 * RDIM + y0) * RDIM + x0) * FDIM;
        int b101 = ((z1 * RDIM + y0) * RDIM + x1) * FDIM;
        int b110 = ((z1 * RDIM + y1) * RDIM + x0) * FDIM;
        int b111 = ((z1 * RDIM + y1) * RDIM + x1) * FDIM;

        const float4* __restrict__ src = (const float4*)voxels;

        float4 v0 = src[(b000 >> 2) + f];
        float4 v1 = src[(b001 >> 2) + f];
        float4 v2 = src[(b010 >> 2) + f];
        float4 v3 = src[(b011 >> 2) + f];
        float4 v4 = src[(b100 >> 2) + f];
        float4 v5 = src[(b101 >> 2) + f];
        float4 v6 = src[(b110 >> 2) + f];
        float4 v7 = src[(b111 >> 2) + f];

        float4 acc;
        acc.x = w000 * v0.x + w001 * v1.x + w010 * v2.x + w011 * v3.x
              + w100 * v4.x + w101 * v5.x + w110 * v6.x + w111 * v7.x;
        acc.y = w000 * v0.y + w001 * v1.y + w010 * v2.y + w011 * v3.y
              + w100 * v4.y + w101 * v5.y + w110 * v6.y + w111 * v7.y;
        acc.z = w000 * v0.z + w001 * v1.z + w010 * v2.z + w011 * v3.z
              + w100 * v4.z + w101 * v5.z + w110 * v6.z + w111 * v7.z;
        acc.w = w000 * v0.w + w001 * v1.w + w010 * v2.w + w011 * v3.w
              + w100 * v4.w + w101 * v5.w + w110 * v6.w + w111 * v7.w;

        *(float4*)&feats[group][4 * f] = acc;
    }

    __syncthreads();

    if (tid < PTS_PER_BLOCK) {
        int p2 = blockIdx.x * PTS_PER_BLOCK + tid;
        if (p2 < N) {
            float4 pt = sorted[p2];
            float px = pt.x, py = pt.y, pz = pt.z;

            float inv = rsqrtf(px * px + py * py + pz * pz);
            float dx = px * inv, dy = py * inv, dz = pz * inv;

            float basis[9];
            basis[0] = SH_C0;
            basis[1] = SH_C1 * dy;
            basis[2] = SH_C1 * dz;
            basis[3] = SH_C1 * dx;
            basis[4] = SH_C2 * dx * dy;
            basis[5] = SH_C2 * dy * dz;
            basis[6] = SH_C20 * (3.0f * dz * dz - 1.0f);
            basis[7] = SH_C2 * dx * dz;
            basis[8] = SH_C22 * (dx * dx - dy * dy);

            float rgb[3];
#pragma unroll
            for (int c = 0; c < 3; ++c) {
                float s = 0.0f;
#pragma unroll
                for (int j = 0; j < 9; ++j) {
                    s += feats[tid][1 + 9 * c + j] * basis[j];
                }
                rgb[c] = 1.0f / (1.0f + expf(-s));
            }

            float x = feats[tid][0];
            float sig = fmaxf(x, 0.0f) + log1pf(expf(-fabsf(x)));

            tmp[p2] = make_float4(rgb[0], rgb[1], rgb[2], sig);  // coalesced
        }
    }
}

// ---------------------------------------------------------------- permute back
__global__ __launch_bounds__(256)
void permute_kernel(const float4* __restrict__ tmp, const int* __restrict__ rank,
                    float* __restrict__ out_rgb, float* __restrict__ out_sigma, int N) {
    int i = blockIdx.x * 256 + threadIdx.x;
    if (i >= N) return;
    float4 v = tmp[rank[i]];   // scattered 16B read, tmp (32MB) is L3-resident
    out_rgb[3 * i + 0] = v.x;  // coalesced writes
    out_rgb[3 * i + 1] = v.y;
    out_rgb[3 * i + 2] = v.z;
    out_sigma[i] = v.w;
}

extern "C" void kernel_launch(void* const* d_in, const int* in_sizes, int n_in,
                              void* d_out, int out_size, void* d_ws, size_t ws_size,
                              hipStream_t stream) {
    const float* points = (const float*)d_in[0];
    const float* voxels = (const float*)d_in[1];
    int N = in_sizes[0] / 3;

    float* out_rgb = (float*)d_out;              // N*3
    float* out_sigma = out_rgb + (size_t)3 * N;  // N

    // workspace layout (~74 MB of the ~3 GB ws)
    char* ws = (char*)d_ws;
    float4* sorted = (float4*)ws;                          // N*16B
    float4* tmp    = (float4*)(ws + (size_t)N * 16);       // N*16B
    int*    rank   = (int*)(ws + (size_t)N * 32);          // N*4B
    int*    hist   = (int*)(ws + (size_t)N * 36);          // HTOT*4B
    int*    offs   = hist + HTOT;                          // HTOT*4B

    int pblocks = (N + 255) / 256;

    zero_hist<<<(HTOT + 255) / 256, 256, 0, stream>>>(hist);
    hist_kernel<<<pblocks, 256, 0, stream>>>(points, hist, N);
    scan_kernel<<<1, SCAN_T, 0, stream>>>(hist, offs);
    scatter_kernel<<<pblocks, 256, 0, stream>>>(points, offs, sorted, rank, N);

    int gblocks = (N + PTS_PER_BLOCK - 1) / PTS_PER_BLOCK;
    plenoxel_fwd<<<gblocks, 256, 0, stream>>>(sorted, voxels, tmp, N);

    permute_kernel<<<pblocks, 256, 0, stream>>>(tmp, rank, out_rgb, out_sigma, N);
}